// Round 26
// baseline (128.543 us; speedup 1.0000x reference)
//
#include <hip/hip_runtime.h>

typedef unsigned short u16;
typedef __bf16 b16x8_t __attribute__((ext_vector_type(8)));
typedef unsigned short u16x8 __attribute__((ext_vector_type(8)));
typedef float f32x4 __attribute__((ext_vector_type(4)));

__device__ __forceinline__ u16 f2bf(float f) {
  union { float f; unsigned u; } x; x.f = f;
  unsigned r = x.u + 0x7fffu + ((x.u >> 16) & 1u);
  return (u16)(r >> 16);
}

__device__ __forceinline__ f32x4 mfma16(u16x8 a, u16x8 b, f32x4 c) {
  return __builtin_amdgcn_mfma_f32_16x16x32_bf16(
      __builtin_bit_cast(b16x8_t, a), __builtin_bit_cast(b16x8_t, b), c, 0, 0, 0);
}

__device__ __forceinline__ void gld_lds16(const void* g, void* l) {
  __builtin_amdgcn_global_load_lds(
      (const __attribute__((address_space(1))) void*)g,
      (__attribute__((address_space(3))) void*)l, 16, 0, 0);
}

__device__ __forceinline__ void store_out(float* p, float v) { *p = v; }
__device__ __forceinline__ void store_out(u16* p, float v) { *p = f2bf(v); }

// ---------------- fused prep: convert x->bf16 + transpose Pi + transpose Po ---
__global__ __launch_bounds__(256) void prep(const float* __restrict__ x,
                                            u16* __restrict__ xbf,
                                            const float* __restrict__ Pi,
                                            u16* __restrict__ piT,
                                            const float* __restrict__ Po,
                                            u16* __restrict__ poT) {
  __shared__ float t[32][33];
  const int bid = blockIdx.x, tid = threadIdx.x;
  if (bid < 8192) {
    int i = bid * 256 + tid;
    float4 f = ((const float4*)x)[i];
    u16 a0 = f2bf(f.x), a1 = f2bf(f.y), a2 = f2bf(f.z), a3 = f2bf(f.w);
    unsigned lo = (unsigned)a0 | ((unsigned)a1 << 16);
    unsigned hi = (unsigned)a2 | ((unsigned)a3 << 16);
    ((uint2*)xbf)[i] = make_uint2(lo, hi);
    return;
  }
  const float* src; u16* dst; int R, Cn, bx, by;
  if (bid < 11264) {
    int tb = bid - 8192;  src = Pi; dst = piT; R = 1024; Cn = 3072;
    bx = tb % 96; by = tb / 96;
  } else {
    int tb = bid - 11264; src = Po; dst = poT; R = 1024; Cn = 1024;
    bx = tb % 32; by = tb / 32;
  }
  const int tx = tid & 31, ty = tid >> 5;
  const int c0 = bx * 32, r0 = by * 32;
  for (int j = 0; j < 32; j += 8)
    t[ty + j][tx] = src[(size_t)(r0 + ty + j) * Cn + c0 + tx];
  __syncthreads();
  for (int j = 0; j < 32; j += 8)
    dst[(size_t)(c0 + ty + j) * R + r0 + tx] = f2bf(t[tx][ty + j]);
}

// ------- GEMM1 BK=64 single-fence: 1 barrier + 1 fence + 1 drain per K-64 -----
// R24/R25's winning ping-pong, with the two per-substep fences MERGED: preload
// all 20 frag reads (af[4][2], bf[6][2] ~ 80 VGPR), ONE lgkm(0)+fence, one
// 48-MFMA cluster. Longer uninterrupted MFMA window -> better cross-block
// overlap (m114). Hazard structure identical to R24 (fence-merge is within a
// wave's own program order). Regs ~206 < 256; LDS 80KB -> 2 blocks/CU.
__global__ __launch_bounds__(256) void gemm_bk64f(const u16* __restrict__ A,
                                                  const u16* __restrict__ Bt,
                                                  u16* __restrict__ C,
                                                  u16* __restrict__ Vt,
                                                  int M, int N, int K) {
  __shared__ __align__(16) u16 sA[2][8192];    // [buf][128 rows x 64 k]
  __shared__ __align__(16) u16 sB[2][12288];   // [buf][192 rows x 64 k]
  const int tid = threadIdx.x, lane = tid & 63, wid = tid >> 6;
  const int hi = lane >> 4, ln = lane & 15;
  const int wm = (wid >> 1) * 64, wn = (wid & 1) * 96;

  const int gdx = gridDim.x;
  const int nwg = gdx * gridDim.y;
  int wg = blockIdx.y * gdx + blockIdx.x;
  wg = (wg & 7) * (nwg >> 3) + (wg >> 3);
  const int m0 = (wg / gdx) * 128;
  const int n0 = (wg % gdx) * 192;

  const int sr = tid >> 3;
  const int ssw = ((tid & 7) ^ (sr & 7)) * 8;
  const u16* srcA = A + (size_t)(m0 + sr) * K + ssw;
  const u16* srcB = Bt + (size_t)(n0 + sr) * K + ssw;
  const size_t K32 = (size_t)32 * K;

  auto stage = [&](int buf, int t) {
    const int k0 = t * 64;
#pragma unroll
    for (int g = 0; g < 4; ++g)
      gld_lds16(srcA + (size_t)g * K32 + k0, &sA[buf][g * 2048 + tid * 8]);
#pragma unroll
    for (int g = 0; g < 6; ++g)
      gld_lds16(srcB + (size_t)g * K32 + k0, &sB[buf][g * 2048 + tid * 8]);
  };

  int offA[4][2], offB[6][2];
#pragma unroll
  for (int i = 0; i < 4; ++i) {
    int row = wm + i * 16 + ln;
#pragma unroll
    for (int s = 0; s < 2; ++s)
      offA[i][s] = row * 64 + (((s * 4 + hi) ^ (ln & 7)) * 8);
  }
#pragma unroll
  for (int j = 0; j < 6; ++j) {
    int row = wn + j * 16 + ln;
#pragma unroll
    for (int s = 0; s < 2; ++s)
      offB[j][s] = row * 64 + (((s * 4 + hi) ^ (ln & 7)) * 8);
  }

  f32x4 acc[4][6] = {};
  const int NT = K >> 6;  // 16

  stage(0, 0);
  asm volatile("s_waitcnt vmcnt(0)" ::: "memory");
  __builtin_amdgcn_s_barrier();

  for (int kt = 0; kt < NT; ++kt) {
    const int cb = kt & 1;
    if (kt + 1 < NT) stage(cb ^ 1, kt + 1);   // early issue; latency spans iter
    u16x8 af[4][2], bf[6][2];
#pragma unroll
    for (int s = 0; s < 2; ++s) {
#pragma unroll
      for (int i = 0; i < 4; ++i) af[i][s] = *(const u16x8*)(&sA[cb][offA[i][s]]);
#pragma unroll
      for (int j = 0; j < 6; ++j) bf[j][s] = *(const u16x8*)(&sB[cb][offB[j][s]]);
    }
    asm volatile("s_waitcnt lgkmcnt(0)" ::: "memory");   // the ONE fence
    __builtin_amdgcn_sched_barrier(0);
    __builtin_amdgcn_s_setprio(1);
#pragma unroll
    for (int s = 0; s < 2; ++s)
#pragma unroll
      for (int i = 0; i < 4; ++i)
#pragma unroll
        for (int j = 0; j < 6; ++j)
          acc[i][j] = mfma16(af[i][s], bf[j][s], acc[i][j]);
    __builtin_amdgcn_s_setprio(0);
    __builtin_amdgcn_sched_barrier(0);
    asm volatile("s_waitcnt vmcnt(0)" ::: "memory");     // tile kt+1 landed
    __builtin_amdgcn_s_barrier();                        // the ONE barrier
  }

  // epilogue: col = lane&15, row = (lane>>4)*4 + reg
#pragma unroll
  for (int i = 0; i < 4; ++i) {
    int rr = m0 + wm + i * 16 + hi * 4;
#pragma unroll
    for (int j = 0; j < 6; ++j) {
      int colw = wn + j * 16 + ln;
      if (colw >= 128) {
        int h = n0 / 192, kk = colw - 128;
        int b = rr >> 10, n = rr & 1023;
        ushort4 pk;
        pk.x = f2bf(acc[i][j][0]); pk.y = f2bf(acc[i][j][1]);
        pk.z = f2bf(acc[i][j][2]); pk.w = f2bf(acc[i][j][3]);
        *(ushort4*)(Vt + ((size_t)(b * 16 + h) * 64 + kk) * 1024 + n) = pk;
      } else {
        float sc = (colw < 64) ? 0.125f : 1.f;
        int col = n0 + colw;
#pragma unroll
        for (int r = 0; r < 4; ++r)
          C[(size_t)(rr + r) * N + col] = f2bf(acc[i][j][r] * sc);
      }
    }
  }
}

// ------- bf16 GEMM BK=64 ping-pong (GEMM2, R25-proven) ------------------------
template <typename OutT, int BN, int EPI>
__global__ __launch_bounds__(256) void gemm_bk64(const u16* __restrict__ A,
                                                 const u16* __restrict__ Bt,
                                                 OutT* __restrict__ C,
                                                 u16* __restrict__ Vt,
                                                 int M, int N, int K) {
  constexpr int NJ = BN / 32;
  constexpr int NGB = BN / 32;
  __shared__ __align__(16) u16 sA[2][8192];
  __shared__ __align__(16) u16 sB[2][BN * 64];
  const int tid = threadIdx.x, lane = tid & 63, wid = tid >> 6;
  const int hi = lane >> 4, ln = lane & 15;
  const int wm = (wid >> 1) * 64, wn = (wid & 1) * (BN / 2);

  const int gdx = gridDim.x;
  const int nwg = gdx * gridDim.y;
  int wg = blockIdx.y * gdx + blockIdx.x;
  wg = (wg & 7) * (nwg >> 3) + (wg >> 3);
  const int m0 = (wg / gdx) * 128;
  const int n0 = (wg % gdx) * BN;

  const int sr = tid >> 3;
  const int ssw = ((tid & 7) ^ (sr & 7)) * 8;
  const u16* srcA = A + (size_t)(m0 + sr) * K + ssw;
  const u16* srcB = Bt + (size_t)(n0 + sr) * K + ssw;
  const size_t K32 = (size_t)32 * K;

  auto stage = [&](int buf, int t) {
    const int k0 = t * 64;
#pragma unroll
    for (int g = 0; g < 4; ++g)
      gld_lds16(srcA + (size_t)g * K32 + k0, &sA[buf][g * 2048 + tid * 8]);
#pragma unroll
    for (int g = 0; g < NGB; ++g)
      gld_lds16(srcB + (size_t)g * K32 + k0, &sB[buf][g * 2048 + tid * 8]);
  };

  int offA[4][2], offB[NJ][2];
#pragma unroll
  for (int i = 0; i < 4; ++i) {
    int row = wm + i * 16 + ln;
#pragma unroll
    for (int s = 0; s < 2; ++s)
      offA[i][s] = row * 64 + (((s * 4 + hi) ^ (ln & 7)) * 8);
  }
#pragma unroll
  for (int j = 0; j < NJ; ++j) {
    int row = wn + j * 16 + ln;
#pragma unroll
    for (int s = 0; s < 2; ++s)
      offB[j][s] = row * 64 + (((s * 4 + hi) ^ (ln & 7)) * 8);
  }

  f32x4 acc[4][NJ] = {};
  const int NT = K >> 6;

  stage(0, 0);
  asm volatile("s_waitcnt vmcnt(0)" ::: "memory");
  __builtin_amdgcn_s_barrier();

  for (int kt = 0; kt < NT; ++kt) {
    const int cb = kt & 1;
    if (kt + 1 < NT) stage(cb ^ 1, kt + 1);
#pragma unroll
    for (int s = 0; s < 2; ++s) {
      u16x8 af[4], bf[NJ];
#pragma unroll
      for (int i = 0; i < 4; ++i) af[i] = *(const u16x8*)(&sA[cb][offA[i][s]]);
#pragma unroll
      for (int j = 0; j < NJ; ++j) bf[j] = *(const u16x8*)(&sB[cb][offB[j][s]]);
      asm volatile("s_waitcnt lgkmcnt(0)" ::: "memory");
      __builtin_amdgcn_sched_barrier(0);
      __builtin_amdgcn_s_setprio(1);
#pragma unroll
      for (int i = 0; i < 4; ++i)
#pragma unroll
        for (int j = 0; j < NJ; ++j)
          acc[i][j] = mfma16(af[i], bf[j], acc[i][j]);
      __builtin_amdgcn_s_setprio(0);
      __builtin_amdgcn_sched_barrier(0);
    }
    asm volatile("s_waitcnt vmcnt(0)" ::: "memory");
    __builtin_amdgcn_s_barrier();
  }

#pragma unroll
  for (int i = 0; i < 4; ++i) {
    int rr = m0 + wm + i * 16 + hi * 4;
#pragma unroll
    for (int j = 0; j < NJ; ++j) {
      int colw = wn + j * 16 + ln;
      float sc = (EPI == 1 && colw < 64) ? 0.125f : 1.f;
      int col = n0 + colw;
#pragma unroll
      for (int r = 0; r < 4; ++r)
        store_out(&C[(size_t)(rr + r) * N + col], acc[i][j][r] * sc);
    }
  }
}

// ---------------- causal flash attention v7: merged halves + XCD KV locality --
__global__ __launch_bounds__(512, 4) void attn_fwd7(const u16* __restrict__ QKV,
                                                    const u16* __restrict__ Vt,
                                                    u16* __restrict__ O) {
  __shared__ __align__(16) u16 sK[2][4096];
  __shared__ __align__(16) u16 sVt[2][4096];
  __shared__ __align__(16) u16 sP[8][16 * 72];
  const int tid = threadIdx.x, lane = tid & 63, wid = tid >> 6;
  const int bid = blockIdx.x;
  const int w = (bid & 7) * 64 + (bid >> 3);
  const int z = w & 3, h = (w >> 2) & 15, bb = w >> 6;
  const size_t rowbase = (size_t)bb * 1024;
  const size_t vbase = ((size_t)bb * 16 + h) * 64;
  const int colQ = h * 192, colK = colQ + 64;
  const int hi = lane >> 4, ln = lane & 15;
  const int slr = lane >> 3;
  const int sle = ((lane & 7) ^ slr) * 8;
  u16* sPw = sP[wid];
  const u16x8 onesf = {0x3F80, 0x3F80, 0x3F80, 0x3F80, 0x3F80, 0x3F80, 0x3F80, 0x3F80};

  auto stageKV = [&](int buf, int nt) {
    const int n0g = nt * 64;
    gld_lds16(QKV + (rowbase + n0g + 8 * wid + slr) * 3072 + colK + sle,
              &sK[buf][wid * 512]);
    gld_lds16(Vt + (vbase + 8 * wid + slr) * 1024 + n0g + sle,
              &sVt[buf][wid * 512]);
  };

  const int mtA = z, mtB = 7 - z;
  const int qrow0A = mtA * 128 + wid * 16;
  const int qrow0B = mtB * 128 + wid * 16;
  const int ntA = 2 * mtA + 2, ntB = 2 * mtB + 2;

  u16x8 qfA[2], qfB[2];
#pragma unroll
  for (int kb = 0; kb < 2; ++kb) {
    qfA[kb] = *(const u16x8*)(QKV + (rowbase + qrow0A + ln) * 3072 + colQ + kb * 32 + hi * 8);
    qfB[kb] = *(const u16x8*)(QKV + (rowbase + qrow0B + ln) * 3072 + colQ + kb * 32 + hi * 8);
  }

  f32x4 oA[4] = {}, oB[4] = {};
  f32x4 laccA = {0.f, 0.f, 0.f, 0.f}, laccB = {0.f, 0.f, 0.f, 0.f};

  auto computeHalf = [&](const u16x8* qf, f32x4* o, f32x4& lacc, int qrow0,
                         int buf, int n0g) {
    f32x4 s[4] = {};
    __builtin_amdgcn_s_setprio(1);
#pragma unroll
    for (int kb = 0; kb < 2; ++kb)
#pragma unroll
      for (int j = 0; j < 4; ++j) {
        int row = j * 16 + ln;
        int cb = (kb * 64 + hi * 16) ^ ((row & 7) << 4);
        u16x8 kfr = *(const u16x8*)(&sK[buf][(row * 128 + cb) >> 1]);
        s[j] = mfma16(qf[kb], kfr, s[j]);
      }
    __builtin_amdgcn_s_setprio(0);
    if (n0g + 63 > qrow0) {
#pragma unroll
      for (int j = 0; j < 4; ++j) {
        int col = n0g + j * 16 + ln;
#pragma unroll
        for (int r = 0; r < 4; ++r)
          if (col > qrow0 + hi * 4 + r) s[j][r] = -3e38f;
      }
    }
#pragma unroll
    for (int j = 0; j < 4; ++j)
#pragma unroll
      for (int r = 0; r < 4; ++r)
        sPw[(hi * 4 + r) * 72 + j * 16 + ln] = f2bf(__expf(s[j][r]));
    u16x8 pf[2];
#pragma unroll
    for (int kb2 = 0; kb2 < 2; ++kb2)
      pf[kb2] = *(const u16x8*)(&sPw[ln * 72 + kb2 * 32 + hi * 8]);
    __builtin_amdgcn_s_setprio(1);
    lacc = mfma16(pf[0], onesf, lacc);
    lacc = mfma16(pf[1], onesf, lacc);
#pragma unroll
    for (int dt = 0; dt < 4; ++dt)
#pragma unroll
      for (int kb2 = 0; kb2 < 2; ++kb2) {
        int row = dt * 16 + ln;
        int cb = (kb2 * 64 + hi * 16) ^ ((row & 7) << 4);
        u16x8 vfr = *(const u16x8*)(&sVt[buf][(row * 128 + cb) >> 1]);
        o[dt] = mfma16(pf[kb2], vfr, o[dt]);
      }
    __builtin_amdgcn_s_setprio(0);
  };

  stageKV(0, 0);
  for (int nt = 0; nt < ntB; ++nt) {
    __syncthreads();
    if (nt + 1 < ntB) stageKV((nt + 1) & 1, nt + 1);
    const int buf = nt & 1;
    const int n0g = nt * 64;
    if (nt < ntA && n0g <= qrow0A + 15) computeHalf(qfA, oA, laccA, qrow0A, buf, n0g);
    if (n0g <= qrow0B + 15)             computeHalf(qfB, oB, laccB, qrow0B, buf, n0g);
  }

#pragma unroll
  for (int r = 0; r < 4; ++r) {
    float invA = 1.f / laccA[r];
    float invB = 1.f / laccB[r];
#pragma unroll
    for (int dt = 0; dt < 4; ++dt) {
      O[(rowbase + qrow0A + hi * 4 + r) * 1024 + h * 64 + dt * 16 + ln] =
          f2bf(oA[dt][r] * invA);
      O[(rowbase + qrow0B + hi * 4 + r) * 1024 + h * 64 + dt * 16 + ln] =
          f2bf(oB[dt][r] * invB);
    }
  }
}

extern "C" void kernel_launch(void* const* d_in, const int* in_sizes, int n_in,
                              void* d_out, int out_size, void* d_ws, size_t ws_size,
                              hipStream_t stream) {
  const float* x = (const float*)d_in[0];
  const float* Pi = (const float*)d_in[1];
  const float* Po = (const float*)d_in[2];
  float* y = (float*)d_out;
  char* ws = (char*)d_ws;

  u16* qkv  = (u16*)(ws);                     // 0        .. 50331648
  u16* piT  = (u16*)(ws + 50331648);          // 50331648 .. 56623104
  u16* poT  = (u16*)(ws + 56623104);          // 56623104 .. 58720256
  u16* xbf  = (u16*)(ws + 58720256);          // 58720256 .. 75497472 (dead after GEMM1)
  u16* vt   = (u16*)(ws + 75497472);          // 75497472 .. 92274688
  u16* obuf = (u16*)(ws + 58720256);          // reuses xbf slot

  prep<<<12288, 256, 0, stream>>>(x, xbf, Pi, piT, Po, poT);

  gemm_bk64f<<<dim3(16, 64), 256, 0, stream>>>(xbf, piT, qkv, vt, 8192, 3072, 1024);
  attn_fwd7<<<512, 512, 0, stream>>>(qkv, vt, obuf);
  gemm_bk64<float, 128, 0><<<dim3(8, 64), 256, 0, stream>>>(obuf, poT, y, nullptr,
                                                            8192, 1024, 1024);
}